// Round 2
// baseline (909.741 us; speedup 1.0000x reference)
//
#include <hip/hip_runtime.h>

#define AGENT_ID 10

// One wave (64 lanes) per batch item, grid-stride over batches.
// Each lane register-holds its column of W1/W2 and row of W3.
__global__ __launch_bounds__(256) void idm_kernel(
    const int* __restrict__ frames,      // (2,B,32,32,3) int32
    const int* __restrict__ ccol,        // (2,B,1) int32
    const int* __restrict__ cobj,        // (2,B,1) int32
    const float* __restrict__ W1,        // (18,64)
    const float* __restrict__ b1,        // (64,)
    const float* __restrict__ W2,        // (64,64)
    const float* __restrict__ b2,        // (64,)
    const float* __restrict__ W3,        // (64,8)
    const float* __restrict__ b3,        // (8,)
    float* __restrict__ out,             // (B,8) float32
    int B, int nwaves)
{
    const int lane = threadIdx.x & 63;
    const int wave = blockIdx.x * (blockDim.x >> 6) + (threadIdx.x >> 6);

    // ---- register-held weights (per-lane columns/rows) ----
    float w1r[18], w2r[64], w3r[8], b3r[8];
#pragma unroll
    for (int i = 0; i < 18; ++i) w1r[i] = W1[i * 64 + lane];
    const float b1r = b1[lane];
#pragma unroll
    for (int k = 0; k < 64; ++k) w2r[k] = W2[k * 64 + lane];
    const float b2r = b2[lane];
#pragma unroll
    for (int m = 0; m < 8; ++m) w3r[m] = W3[lane * 8 + m];
#pragma unroll
    for (int m = 0; m < 8; ++m) b3r[m] = b3[m];

    for (int b = wave; b < B; b += nwaves) {
        const int* cf = frames + (size_t)b * 3072;        // curr frame
        const int* nf = frames + (size_t)(B + b) * 3072;  // next frame

        // ---- early-exit row-major scan for first agent cell ----
        int first = -1;
#pragma unroll 1
        for (int chunk = 0; chunk < 16; ++chunk) {
            int v = cf[(chunk * 64 + lane) * 3];
            unsigned long long m = __ballot(v == AGENT_ID);
            if (m) { first = chunk * 64 + __ffsll((long long)m) - 1; break; }
        }
        int y, x;
        if (first >= 0) { y = first >> 5; x = first & 31; }
        else            { y = 16;         x = 16;         }

        // ---- gather features (uniform across wave -> broadcast loads) ----
        const int base = (y * 32 + x) * 3;
        const int c0 = cf[base], c1 = cf[base + 1], c2 = cf[base + 2];
        const int curr_dir = c2;
        const int d = curr_dir & 3;  // curr_dir >= 0
        // DIR_TO_VEC = {{1,0},{0,1},{-1,0},{0,-1}}  (dy,dx)
        const int dy = (d == 0) ? 1 : (d == 2) ? -1 : 0;
        const int dx = (d == 1) ? 1 : (d == 3) ? -1 : 0;
        const int y2 = y + dy, x2 = x + dx;
        const bool inb = (y2 >= 0) && (y2 < 32) && (x2 >= 0) && (x2 < 32);
        int f0 = 0, f1 = 0, f2 = 0, g0 = 0, g1 = 0, g2 = 0;
        const int base2 = (y2 * 32 + x2) * 3;
        if (inb) {
            f0 = cf[base2]; f1 = cf[base2 + 1]; f2 = cf[base2 + 2];
            g0 = nf[base2]; g1 = nf[base2 + 1]; g2 = nf[base2 + 2];
        }
        const int n0 = nf[base], n1 = nf[base + 1], n2 = nf[base + 2];
        const int next_dir = n2;  // nxt[b,y,x,2]

        // direction delta encoding; (next-curr+4) mod 4, python-style mod
        const int delta = (next_dir - curr_dir + 12) & 3;  // +12 keeps it >= 0
        const float ang = (float)delta * 1.5707950f;       // 2*3.14159/4
        const float s = sinf(ang), c = cosf(ang);

        float cmb[18];
        cmb[0] = (float)c0;  cmb[1] = (float)c1;  cmb[2] = (float)c2;
        cmb[3] = (float)f0;  cmb[4] = (float)f1;  cmb[5] = (float)f2;
        cmb[6] = (float)n0;  cmb[7] = (float)n1;  cmb[8] = (float)n2;
        cmb[9] = (float)g0;  cmb[10] = (float)g1; cmb[11] = (float)g2;
        cmb[12] = (float)ccol[b];
        cmb[13] = (float)cobj[b];
        cmb[14] = (float)ccol[B + b];
        cmb[15] = (float)cobj[B + b];
        cmb[16] = s; cmb[17] = c;

        // ---- MLP layer 1: lane j computes h1[j] ----
        float h1 = b1r;
#pragma unroll
        for (int i = 0; i < 18; ++i) h1 = fmaf(cmb[i], w1r[i], h1);
        h1 = fmaxf(h1, 0.0f);

        // ---- layer 2: broadcast h1[k] to all lanes (readlane) ----
        float h2 = b2r;
#pragma unroll
        for (int k = 0; k < 64; ++k) {
            float hk = __shfl(h1, k);
            h2 = fmaf(hk, w2r[k], h2);
        }
        h2 = fmaxf(h2, 0.0f);

        // ---- layer 3: distributed partials + butterfly reduce ----
        float p[8];
#pragma unroll
        for (int m = 0; m < 8; ++m)
            p[m] = fmaf(h2, w3r[m], (lane == 0) ? b3r[m] : 0.0f);
#pragma unroll
        for (int mask = 1; mask < 64; mask <<= 1) {
#pragma unroll
            for (int m = 0; m < 8; ++m) p[m] += __shfl_xor(p[m], mask);
        }
        // now every lane holds the full out[0..7]; lanes 0..7 write
        if (lane < 8) {
            float v = p[0];
            if (lane == 1) v = p[1];
            if (lane == 2) v = p[2];
            if (lane == 3) v = p[3];
            if (lane == 4) v = p[4];
            if (lane == 5) v = p[5];
            if (lane == 6) v = p[6];
            if (lane == 7) v = p[7];
            out[(size_t)b * 8 + lane] = v;
        }
    }
}

extern "C" void kernel_launch(void* const* d_in, const int* in_sizes, int n_in,
                              void* d_out, int out_size, void* d_ws, size_t ws_size,
                              hipStream_t stream) {
    const int*   frames = (const int*)d_in[0];
    const int*   ccol   = (const int*)d_in[1];
    const int*   cobj   = (const int*)d_in[2];
    const float* W1     = (const float*)d_in[3];
    const float* b1     = (const float*)d_in[4];
    const float* W2     = (const float*)d_in[5];
    const float* b2     = (const float*)d_in[6];
    const float* W3     = (const float*)d_in[7];
    const float* b3     = (const float*)d_in[8];
    float* out = (float*)d_out;

    const int B = in_sizes[1] / 2;   // carried_col has 2*B elements
    const int blocks = 2048;         // 4 waves/block -> 8192 waves, 4 batches/wave
    const int nwaves = blocks * (256 / 64);

    idm_kernel<<<blocks, 256, 0, stream>>>(frames, ccol, cobj,
                                           W1, b1, W2, b2, W3, b3,
                                           out, B, nwaves);
}